// Round 11
// baseline (197.981 us; speedup 1.0000x reference)
//
#include <hip/hip_runtime.h>
#include <hip/hip_bf16.h>
#include <math.h>

#define N_NODES 100000
#define N_EDGES 1250000
#define D_IN    64
#define D_HID   64
#define N_CLS   40

#define NBUCK      391       // ceil(100000/256) buckets of BUCK_NODES nodes
#define BUCK_NODES 256       // pow2: bucket id = dst >> 8
#define BUCK_CAP   3712      // mean 3200, sigma ~57 -> +9 sigma headroom
#define NBLK_STAGE 512       // blockIdx.x % 3 == 0 -> stage role (interleaved)
#define NBLK_GEMM1 1024
#define ELL_W      44        // Poisson(12.5) tail @44 ~ 3e-12/node
#define GNODES     64        // nodes per gather block (quarter bucket: grid 1564)
#define HPAD       80        // h row stride in LDS (elements); 160B, 16B-aligned

typedef unsigned int uint;
typedef __attribute__((ext_vector_type(8))) short bf16x8;
typedef __attribute__((ext_vector_type(4))) float f32x4;

static __device__ __forceinline__ uint pack_bf16x2(float a, float b) {
    unsigned short ua = __builtin_bit_cast(unsigned short, __float2bfloat16(a));
    unsigned short ub = __builtin_bit_cast(unsigned short, __float2bfloat16(b));
    return (uint)ua | ((uint)ub << 16);
}
static __device__ __forceinline__ short f2bf(float f) {
    return (short)__builtin_bit_cast(unsigned short, __float2bfloat16(f));
}

// 16-edge gather step, 64-wide rows (K2): DIRECT-index bpermute -> y1 row
// load -> unpack-accumulate.  2-deep chain, zero guards (pad lanes carry
// idx == N_NODES, the zeroed dummy row).
static __device__ __forceinline__ void gath16_64(
    const char* __restrict__ y1c, int e, int q4, uint pre, int idx,
    float& a0, float& a1, float& a2, float& a3)
{
    int s0 = __builtin_amdgcn_ds_bpermute(e * 4      + q4, idx);
    int s1 = __builtin_amdgcn_ds_bpermute(e * 4 + 16 + q4, idx);
    int s2 = __builtin_amdgcn_ds_bpermute(e * 4 + 32 + q4, idx);
    int s3 = __builtin_amdgcn_ds_bpermute(e * 4 + 48 + q4, idx);
    uint2 d0 = *(const uint2*)(y1c + ((size_t)(uint)s0 * 128u + pre));
    uint2 d1 = *(const uint2*)(y1c + ((size_t)(uint)s1 * 128u + pre));
    uint2 d2 = *(const uint2*)(y1c + ((size_t)(uint)s2 * 128u + pre));
    uint2 d3 = *(const uint2*)(y1c + ((size_t)(uint)s3 * 128u + pre));
    a0 += __uint_as_float(d0.x << 16) + __uint_as_float(d1.x << 16)
        + __uint_as_float(d2.x << 16) + __uint_as_float(d3.x << 16);
    a1 += __uint_as_float(d0.x & 0xffff0000u) + __uint_as_float(d1.x & 0xffff0000u)
        + __uint_as_float(d2.x & 0xffff0000u) + __uint_as_float(d3.x & 0xffff0000u);
    a2 += __uint_as_float(d0.y << 16) + __uint_as_float(d1.y << 16)
        + __uint_as_float(d2.y << 16) + __uint_as_float(d3.y << 16);
    a3 += __uint_as_float(d0.y & 0xffff0000u) + __uint_as_float(d1.y & 0xffff0000u)
        + __uint_as_float(d2.y & 0xffff0000u) + __uint_as_float(d3.y & 0xffff0000u);
}

// 16-edge gather step, 40-wide rows (K3): direct-idx bpermute -> y2 load.
static __device__ __forceinline__ void gath16_40(
    const char* __restrict__ y2c, int e, int p2, uint pre2, int idx,
    float& a0, float& a1)
{
    int s0 = __builtin_amdgcn_ds_bpermute(e * 4      + p2, idx);
    int s1 = __builtin_amdgcn_ds_bpermute(e * 4 +  8 + p2, idx);
    int s2 = __builtin_amdgcn_ds_bpermute(e * 4 + 16 + p2, idx);
    int s3 = __builtin_amdgcn_ds_bpermute(e * 4 + 24 + p2, idx);
    int s4 = __builtin_amdgcn_ds_bpermute(e * 4 + 32 + p2, idx);
    int s5 = __builtin_amdgcn_ds_bpermute(e * 4 + 40 + p2, idx);
    int s6 = __builtin_amdgcn_ds_bpermute(e * 4 + 48 + p2, idx);
    int s7 = __builtin_amdgcn_ds_bpermute(e * 4 + 56 + p2, idx);
    uint d0 = *(const uint*)(y2c + ((size_t)(uint)s0 * 80u + pre2));
    uint d1 = *(const uint*)(y2c + ((size_t)(uint)s1 * 80u + pre2));
    uint d2 = *(const uint*)(y2c + ((size_t)(uint)s2 * 80u + pre2));
    uint d3 = *(const uint*)(y2c + ((size_t)(uint)s3 * 80u + pre2));
    uint d4 = *(const uint*)(y2c + ((size_t)(uint)s4 * 80u + pre2));
    uint d5 = *(const uint*)(y2c + ((size_t)(uint)s5 * 80u + pre2));
    uint d6 = *(const uint*)(y2c + ((size_t)(uint)s6 * 80u + pre2));
    uint d7 = *(const uint*)(y2c + ((size_t)(uint)s7 * 80u + pre2));
    a0 += __uint_as_float(d0 << 16) + __uint_as_float(d1 << 16)
        + __uint_as_float(d2 << 16) + __uint_as_float(d3 << 16)
        + __uint_as_float(d4 << 16) + __uint_as_float(d5 << 16)
        + __uint_as_float(d6 << 16) + __uint_as_float(d7 << 16);
    a1 += __uint_as_float(d0 & 0xffff0000u) + __uint_as_float(d1 & 0xffff0000u)
        + __uint_as_float(d2 & 0xffff0000u) + __uint_as_float(d3 & 0xffff0000u)
        + __uint_as_float(d4 & 0xffff0000u) + __uint_as_float(d5 & 0xffff0000u)
        + __uint_as_float(d6 & 0xffff0000u) + __uint_as_float(d7 & 0xffff0000u);
}

// ---------------------------------------------------------------------------
// Fused K1: interleaved stage/gemm roles, static partition.
// launch_bounds(256, 4): 4 blocks/CU (16 waves/CU) with VGPR cap 128 —
// live set is 72, so no spill (R8's (256,6) capped at ~85 and spilled to 40;
// spill tripwire = FETCH/WRITE jump).
// ---------------------------------------------------------------------------
__global__ __launch_bounds__(256, 4) void stage_and_gemm1(
    const int* __restrict__ src, const int* __restrict__ dst,
    int* __restrict__ bucketCnt, uint* __restrict__ staged,
    const float* __restrict__ x,
    const float* __restrict__ W_l, const float* __restrict__ W_r,
    const float* __restrict__ b,
    __hip_bfloat16* __restrict__ y1, __hip_bfloat16* __restrict__ r1,
    __hip_bfloat16* __restrict__ y2, int ntiles)
{
    __shared__ int cntB[NBUCK], offB[NBUCK], gbase[NBUCK];

    if (blockIdx.x % 3 == 0) {
        const int sid = blockIdx.x / 3;
        const int per = (N_EDGES + NBLK_STAGE - 1) / NBLK_STAGE;   // 2442
        const int e0 = sid * per;
        const int e1 = (e0 + per < N_EDGES) ? e0 + per : N_EDGES;
        for (int i = threadIdx.x; i < NBUCK; i += 256) { cntB[i] = 0; offB[i] = 0; }
        __syncthreads();
        for (int e = e0 + threadIdx.x; e < e1; e += 256)
            atomicAdd(&cntB[dst[e] >> 8], 1);
        __syncthreads();
        for (int i = threadIdx.x; i < NBUCK; i += 256) {
            int c = cntB[i];
            gbase[i] = c ? atomicAdd(&bucketCnt[i], c) : 0;
        }
        __syncthreads();
        for (int e = e0 + threadIdx.x; e < e1; e += 256) {
            int d = dst[e];
            int s = src[e];
            int bk = d >> 8;
            int pos = gbase[bk] + atomicAdd(&offB[bk], 1);
            if (pos < BUCK_CAP)
                staged[(size_t)bk * BUCK_CAP + pos] =
                    (uint)s | ((uint)(d & 255) << 17);
        }
        return;
    }

    // ---- gemm1: gbid in [0, 1024) ----
    const int gbid = blockIdx.x - (blockIdx.x / 3 + 1);
    if (gbid == 0 && threadIdx.x < 64) {
        y1[(size_t)N_NODES * 64 + threadIdx.x] = __float2bfloat16(0.0f);
        if (threadIdx.x < N_CLS)
            y2[(size_t)N_NODES * N_CLS + threadIdx.x] = __float2bfloat16(0.0f);
    }

    const int lane = threadIdx.x & 63;
    const int m = lane & 15;
    const int q = lane >> 4;

    bf16x8 bfrag[8][2];
    float  biasv[4];
    #pragma unroll
    for (int t = 0; t < 8; ++t) {
        const float* Wsrc = (t < 4) ? W_l : W_r;
        const int c = t * 16 + m - ((t < 4) ? 0 : 64);
        #pragma unroll
        for (int ks = 0; ks < 2; ++ks) {
            bf16x8 f;
            #pragma unroll
            for (int j = 0; j < 8; ++j)
                f[j] = f2bf(Wsrc[(ks * 32 + q * 8 + j) * 64 + c]);
            bfrag[t][ks] = f;
        }
    }
    #pragma unroll
    for (int t = 0; t < 4; ++t) biasv[t] = b[t * 16 + m];

    int wid = gbid * 4 + (threadIdx.x >> 6);
    const int nw = NBLK_GEMM1 * 4;
    for (int tile = wid; tile < ntiles; tile += nw) {
        const int node0 = tile * 16;
        const float* xrow = x + (size_t)(node0 + m) * 64 + q * 8;
        bf16x8 afrag[2];
        #pragma unroll
        for (int ks = 0; ks < 2; ++ks) {
            float4 f0 = *(const float4*)(xrow + ks * 32);
            float4 f1 = *(const float4*)(xrow + ks * 32 + 4);
            bf16x8 a;
            a[0] = f2bf(f0.x); a[1] = f2bf(f0.y); a[2] = f2bf(f0.z); a[3] = f2bf(f0.w);
            a[4] = f2bf(f1.x); a[5] = f2bf(f1.y); a[6] = f2bf(f1.z); a[7] = f2bf(f1.w);
            afrag[ks] = a;
        }
        f32x4 acc[8];
        #pragma unroll
        for (int t = 0; t < 8; ++t) acc[t] = (f32x4){0.f, 0.f, 0.f, 0.f};
        #pragma unroll
        for (int ks = 0; ks < 2; ++ks) {
            #pragma unroll
            for (int t = 0; t < 8; ++t)
                acc[t] = __builtin_amdgcn_mfma_f32_16x16x32_bf16(
                    afrag[ks], bfrag[t][ks], acc[t], 0, 0, 0);
        }
        #pragma unroll
        for (int t = 0; t < 8; ++t) {
            #pragma unroll
            for (int r = 0; r < 4; ++r) {
                const size_t row = (size_t)(node0 + q * 4 + r);
                if (t < 4)
                    y1[row * 64 + t * 16 + m] = __float2bfloat16(acc[t][r]);
                else
                    r1[row * 64 + (t - 4) * 16 + m] =
                        __float2bfloat16(acc[t][r] + biasv[t - 4]);
            }
        }
    }
}

// ---------------------------------------------------------------------------
// K2: LDS-ELL build + pair-pipelined gather + relu + fused gemm2.
// GNODES=64 lets lslots hold FULL src ids as int (11.5 KB): the gather chain
// is 2-deep (bpermute -> row load), no staged re-deref, no inner guards.
// LDS ~22 KB -> 4 blocks/CU (32 waves, the cap); grid 1564 = ~6 blocks/CU
// of work with rotation rounds to smooth stragglers.
// ---------------------------------------------------------------------------
__global__ __launch_bounds__(512, 8) void gather1_gemm2(
    const __hip_bfloat16* __restrict__ y1,   // [N+1][64], row N zeroed
    const uint* __restrict__ staged, const int* __restrict__ bucketCnt,
    const __hip_bfloat16* __restrict__ r1,   // [N][64]
    const float* __restrict__ W_l, const float* __restrict__ W_r,
    const float* __restrict__ b,             // W2_l, W2_r, b2
    __hip_bfloat16* __restrict__ y2, __hip_bfloat16* __restrict__ r2)
{
    __shared__ int   lcnt[GNODES];
    __shared__ int   lslots[GNODES * ELL_W + 64];   // 11.5 KB (src ids)
    __shared__ short hls[GNODES * HPAD];            // 10.25 KB h tile

    const int pb = blockIdx.x >> 2;          // parent staging bucket
    const int qt = blockIdx.x & 3;           // which quarter we own
    const int node0 = pb * BUCK_NODES + qt * GNODES;

    for (int i = threadIdx.x; i < GNODES; i += 512) lcnt[i] = 0;
    __syncthreads();

    int total = bucketCnt[pb]; if (total > BUCK_CAP) total = BUCK_CAP;
    const uint* sp = staged + (size_t)pb * BUCK_CAP;
    const int rel0 = qt * GNODES;
    for (int i = threadIdx.x; i < total; i += 512) {
        uint v = sp[i];
        int rel = (int)(v >> 17) - rel0;
        if (0 <= rel && rel < GNODES) {
            int pos = atomicAdd(&lcnt[rel], 1);
            if (pos < ELL_W) lslots[rel * ELL_W + pos] = (int)(v & 0x1FFFFu);
        }
    }
    __syncthreads();

    const int lane = threadIdx.x & 63;
    const int wv   = threadIdx.x >> 6;       // 0..7
    const int q4   = (lane >> 4) * 4;
    const uint pre = (uint)(lane & 15) * 8u;
    const char* y1c = (const char*)y1;

    for (int n = wv; n < GNODES; n += 16) {
        const int nA = n, nB = n + 8;
        const int nodeA = node0 + nA, nodeB = node0 + nB;
        const bool vA = nodeA < N_NODES, vB = nodeB < N_NODES;
        const int degA = vA ? lcnt[nA] : 0;
        const int degB = vB ? lcnt[nB] : 0;
        const int dcA = degA < ELL_W ? degA : ELL_W;
        const int dcB = degB < ELL_W ? degB : ELL_W;
        const int idxA = (lane >= dcA) ? N_NODES : lslots[nA * ELL_W + lane];
        const int idxB = (lane >= dcB) ? N_NODES : lslots[nB * ELL_W + lane];

        uint2 rrA = *(const uint2*)((const char*)r1 +
                        ((size_t)(vA ? nodeA : 0) * 128u + pre));
        uint2 rrB = *(const uint2*)((const char*)r1 +
                        ((size_t)(vB ? nodeB : 0) * 128u + pre));

        float aA0 = 0.f, aA1 = 0.f, aA2 = 0.f, aA3 = 0.f;
        float aB0 = 0.f, aB1 = 0.f, aB2 = 0.f, aB3 = 0.f;

        gath16_64(y1c, 0, q4, pre, idxA, aA0, aA1, aA2, aA3);
        gath16_64(y1c, 0, q4, pre, idxB, aB0, aB1, aB2, aB3);
        for (int e = 16; e < ((dcA + 15) & ~15); e += 16)
            gath16_64(y1c, e, q4, pre, idxA, aA0, aA1, aA2, aA3);
        for (int e = 16; e < ((dcB + 15) & ~15); e += 16)
            gath16_64(y1c, e, q4, pre, idxB, aB0, aB1, aB2, aB3);

        aA0 += __shfl_xor(aA0, 16); aA0 += __shfl_xor(aA0, 32);
        aA1 += __shfl_xor(aA1, 16); aA1 += __shfl_xor(aA1, 32);
        aA2 += __shfl_xor(aA2, 16); aA2 += __shfl_xor(aA2, 32);
        aA3 += __shfl_xor(aA3, 16); aA3 += __shfl_xor(aA3, 32);
        aB0 += __shfl_xor(aB0, 16); aB0 += __shfl_xor(aB0, 32);
        aB1 += __shfl_xor(aB1, 16); aB1 += __shfl_xor(aB1, 32);
        aB2 += __shfl_xor(aB2, 16); aB2 += __shfl_xor(aB2, 32);
        aB3 += __shfl_xor(aB3, 16); aB3 += __shfl_xor(aB3, 32);

        const float invA = 1.0f / (float)(degA > 1 ? degA : 1);
        const float invB = 1.0f / (float)(degB > 1 ? degB : 1);

        float vA0 = aA0 * invA + __uint_as_float(rrA.x << 16);
        float vA1 = aA1 * invA + __uint_as_float(rrA.x & 0xffff0000u);
        float vA2 = aA2 * invA + __uint_as_float(rrA.y << 16);
        float vA3 = aA3 * invA + __uint_as_float(rrA.y & 0xffff0000u);
        vA0 = vA0 > 0.f ? vA0 : 0.f; vA1 = vA1 > 0.f ? vA1 : 0.f;
        vA2 = vA2 > 0.f ? vA2 : 0.f; vA3 = vA3 > 0.f ? vA3 : 0.f;
        float vB0 = aB0 * invB + __uint_as_float(rrB.x << 16);
        float vB1 = aB1 * invB + __uint_as_float(rrB.x & 0xffff0000u);
        float vB2 = aB2 * invB + __uint_as_float(rrB.y << 16);
        float vB3 = aB3 * invB + __uint_as_float(rrB.y & 0xffff0000u);
        vB0 = vB0 > 0.f ? vB0 : 0.f; vB1 = vB1 > 0.f ? vB1 : 0.f;
        vB2 = vB2 > 0.f ? vB2 : 0.f; vB3 = vB3 > 0.f ? vB3 : 0.f;

        if (lane < 16) {
            uint2 oA, oB;
            oA.x = pack_bf16x2(vA0, vA1); oA.y = pack_bf16x2(vA2, vA3);
            oB.x = pack_bf16x2(vB0, vB1); oB.y = pack_bf16x2(vB2, vB3);
            *(uint2*)(&hls[nA * HPAD + (lane & 15) * 4]) = oA;
            *(uint2*)(&hls[nB * HPAD + (lane & 15) * 4]) = oB;
        }
    }
    __syncthreads();

    // ---- fused gemm2: waves 0-3 each own one 16-row tile (64 rows) ----
    if (wv < 4) {
        const int m = lane & 15;
        const int q = lane >> 4;
        bf16x8 bfrag[5][2];
        float  biasv[5];
        #pragma unroll
        for (int t = 0; t < 5; ++t) {
            const int g = t * 16 + m;
            const float* Wsrc = (g < N_CLS) ? W_l : W_r;
            const int c = (g < N_CLS) ? g : g - N_CLS;
            #pragma unroll
            for (int ks = 0; ks < 2; ++ks) {
                bf16x8 f;
                #pragma unroll
                for (int j = 0; j < 8; ++j)
                    f[j] = f2bf(Wsrc[(ks * 32 + q * 8 + j) * N_CLS + c]);
                bfrag[t][ks] = f;
            }
            biasv[t] = (g >= N_CLS) ? b[g - N_CLS] : 0.0f;
        }

        const int trow0 = wv * 16;
        bf16x8 afrag[2];
        afrag[0] = *(const bf16x8*)(&hls[(trow0 + m) * HPAD + q * 8]);
        afrag[1] = *(const bf16x8*)(&hls[(trow0 + m) * HPAD + 32 + q * 8]);
        f32x4 acc[5];
        #pragma unroll
        for (int t = 0; t < 5; ++t) acc[t] = (f32x4){0.f, 0.f, 0.f, 0.f};
        #pragma unroll
        for (int ks = 0; ks < 2; ++ks) {
            #pragma unroll
            for (int t = 0; t < 5; ++t)
                acc[t] = __builtin_amdgcn_mfma_f32_16x16x32_bf16(
                    afrag[ks], bfrag[t][ks], acc[t], 0, 0, 0);
        }
        const int gnode0 = node0 + trow0;
        #pragma unroll
        for (int t = 0; t < 5; ++t) {
            const int g = t * 16 + m;
            #pragma unroll
            for (int r = 0; r < 4; ++r) {
                const int row = gnode0 + q * 4 + r;
                if (row < N_NODES) {
                    float v = acc[t][r] + biasv[t];
                    if (g < N_CLS) y2[(size_t)row * N_CLS + g] = __float2bfloat16(v);
                    else           r2[(size_t)row * N_CLS + (g - N_CLS)] = __float2bfloat16(v);
                }
            }
        }
    }
}

// ---------------------------------------------------------------------------
// K3: LDS-ELL build + pair-pipelined gather + log_softmax.  GNODES=64:
// grid 1564 -> 4 blocks/CU resident (32 waves).  LDS 11.6 KB.
// ---------------------------------------------------------------------------
__global__ __launch_bounds__(512, 8) void bucket_gather2(
    const __hip_bfloat16* __restrict__ y2,   // [N+1][40], row N zeroed
    const __hip_bfloat16* __restrict__ r2,   // [N][40]
    const uint* __restrict__ staged, const int* __restrict__ bucketCnt,
    float* __restrict__ out)
{
    __shared__ int lcnt[GNODES];
    __shared__ int lslots[GNODES * ELL_W + 64];
    const int pb = blockIdx.x >> 2;
    const int qt = blockIdx.x & 3;
    const int node0 = pb * BUCK_NODES + qt * GNODES;

    for (int i = threadIdx.x; i < GNODES; i += 512) lcnt[i] = 0;
    __syncthreads();

    int total = bucketCnt[pb]; if (total > BUCK_CAP) total = BUCK_CAP;
    const uint* sp = staged + (size_t)pb * BUCK_CAP;
    const int rel0 = qt * GNODES;
    for (int i = threadIdx.x; i < total; i += 512) {
        uint v = sp[i];
        int rel = (int)(v >> 17) - rel0;
        if (0 <= rel && rel < GNODES) {
            int pos = atomicAdd(&lcnt[rel], 1);
            if (pos < ELL_W) lslots[rel * ELL_W + pos] = (int)(v & 0x1FFFFu);
        }
    }
    __syncthreads();

    const int lane  = threadIdx.x & 63;
    const int wv    = threadIdx.x >> 6;
    const int lpair = lane & 31;
    const int p2    = (lane >> 5) * 4;
    const uint pre2 = (uint)(lpair < 20 ? lpair : 19) * 4u;
    const char* y2c = (const char*)y2;

    for (int n = wv; n < GNODES; n += 16) {
        const int nA = n, nB = n + 8;
        const int nodeA = node0 + nA, nodeB = node0 + nB;
        const bool vA = nodeA < N_NODES, vB = nodeB < N_NODES;
        const int degA = vA ? lcnt[nA] : 0;
        const int degB = vB ? lcnt[nB] : 0;
        const int dcA = degA < ELL_W ? degA : ELL_W;
        const int dcB = degB < ELL_W ? degB : ELL_W;
        const int idxA = (lane >= dcA) ? N_NODES : lslots[nA * ELL_W + lane];
        const int idxB = (lane >= dcB) ? N_NODES : lslots[nB * ELL_W + lane];

        uint rrA = *(const uint*)((const char*)r2 +
                       ((size_t)(vA ? nodeA : 0) * 80u + pre2));
        uint rrB = *(const uint*)((const char*)r2 +
                       ((size_t)(vB ? nodeB : 0) * 80u + pre2));

        float aA0 = 0.f, aA1 = 0.f, aB0 = 0.f, aB1 = 0.f;
        gath16_40(y2c, 0, p2, pre2, idxA, aA0, aA1);
        gath16_40(y2c, 0, p2, pre2, idxB, aB0, aB1);
        for (int e = 16; e < ((dcA + 15) & ~15); e += 16)
            gath16_40(y2c, e, p2, pre2, idxA, aA0, aA1);
        for (int e = 16; e < ((dcB + 15) & ~15); e += 16)
            gath16_40(y2c, e, p2, pre2, idxB, aB0, aB1);

        aA0 += __shfl_xor(aA0, 32);
        aA1 += __shfl_xor(aA1, 32);
        aB0 += __shfl_xor(aB0, 32);
        aB1 += __shfl_xor(aB1, 32);

        const float invA = 1.0f / (float)(degA > 1 ? degA : 1);
        const float invB = 1.0f / (float)(degB > 1 ? degB : 1);
        float lA0 = aA0 * invA + __uint_as_float(rrA << 16);
        float lA1 = aA1 * invA + __uint_as_float(rrA & 0xffff0000u);
        float lB0 = aB0 * invB + __uint_as_float(rrB << 16);
        float lB1 = aB1 * invB + __uint_as_float(rrB & 0xffff0000u);
        if (lpair >= 20) { lA0 = -INFINITY; lA1 = -INFINITY;
                           lB0 = -INFINITY; lB1 = -INFINITY; }

        float mA = fmaxf(lA0, lA1);
        float mB = fmaxf(lB0, lB1);
        #pragma unroll
        for (int off = 16; off > 0; off >>= 1) {
            mA = fmaxf(mA, __shfl_xor(mA, off));
            mB = fmaxf(mB, __shfl_xor(mB, off));
        }
        float exA = (lpair < 20) ? (expf(lA0 - mA) + expf(lA1 - mA)) : 0.0f;
        float exB = (lpair < 20) ? (expf(lB0 - mB) + expf(lB1 - mB)) : 0.0f;
        #pragma unroll
        for (int off = 16; off > 0; off >>= 1) {
            exA += __shfl_xor(exA, off);
            exB += __shfl_xor(exB, off);
        }
        float lgA = mA + logf(exA);
        float lgB = mB + logf(exB);
        if (vA && lane < 20) {
            float2 o = make_float2(lA0 - lgA, lA1 - lgA);
            *(float2*)(out + (size_t)nodeA * N_CLS + lpair * 2) = o;
        }
        if (vB && lane < 20) {
            float2 o = make_float2(lB0 - lgB, lB1 - lgB);
            *(float2*)(out + (size_t)nodeB * N_CLS + lpair * 2) = o;
        }
    }
}

extern "C" void kernel_launch(void* const* d_in, const int* in_sizes, int n_in,
                              void* d_out, int out_size, void* d_ws, size_t ws_size,
                              hipStream_t stream)
{
    (void)in_sizes; (void)n_in; (void)out_size; (void)ws_size;

    const float* x    = (const float*)d_in[0];
    const int*   ei   = (const int*)d_in[1];      // [2, E]: src row, then dst row
    const float* W1_l = (const float*)d_in[2];
    const float* b1   = (const float*)d_in[3];
    const float* W1_r = (const float*)d_in[4];
    const float* W2_l = (const float*)d_in[5];
    const float* b2   = (const float*)d_in[6];
    const float* W2_r = (const float*)d_in[7];
    float* out = (float*)d_out;

    const int* src = ei;
    const int* dst = ei + N_EDGES;

    // workspace layout (bytes, ~51 MiB):
    //   bucketCnt : [0, 1564)                int[NBUCK]
    //   staged    : [1M, +5.81MB)            u32[NBUCK*BUCK_CAP]
    //   y1        : [8M, +12.81MB)           bf16[(N+1)*64]
    //   r1        : [21M, +12.8MB)           bf16[N*64]
    //   y2        : [34M, +8.01MB)           bf16[(N+1)*40]
    //   r2        : [43M, +8MB)              bf16[N*40]
    char* ws = (char*)d_ws;
    int*            bucketCnt = (int*)(ws);
    uint*           staged    = (uint*)(ws + 1048576u);
    __hip_bfloat16* y1        = (__hip_bfloat16*)(ws + 8388608u);
    __hip_bfloat16* r1        = (__hip_bfloat16*)(ws + 22020096u);
    __hip_bfloat16* y2        = (__hip_bfloat16*)(ws + 35651584u);
    __hip_bfloat16* r2        = (__hip_bfloat16*)(ws + 45088768u);

    const int ntiles = N_NODES / 16;   // 6250, exact

    // K0: zero bucket counters
    hipMemsetAsync(ws, 0, 4096, stream);

    // K1: edge bucketing || gemm1 (static partition, interleaved roles)
    stage_and_gemm1<<<NBLK_STAGE + NBLK_GEMM1, 256, 0, stream>>>(
        src, dst, bucketCnt, staged, x, W1_l, W1_r, b1, y1, r1, y2, ntiles);

    // K2: LDS-ELL build + pair-pipelined gather (2-deep) + relu + fused gemm2
    gather1_gemm2<<<NBUCK * 4, 512, 0, stream>>>(
        y1, staged, bucketCnt, r1, W2_l, W2_r, b2, y2, r2);

    // K3: LDS-ELL build + pair-pipelined gather + log_softmax
    bucket_gather2<<<NBUCK * 4, 512, 0, stream>>>(y2, r2, staged, bucketCnt, out);
}

// Round 12
// 189.976 us; speedup vs baseline: 1.0421x; 1.0421x over previous
//
#include <hip/hip_runtime.h>
#include <hip/hip_bf16.h>
#include <math.h>

#define N_NODES 100000
#define N_EDGES 1250000
#define D_IN    64
#define D_HID   64
#define N_CLS   40

#define NBUCK      391       // ceil(100000/256) buckets of BUCK_NODES nodes
#define BUCK_NODES 256       // pow2: bucket id = dst >> 8
#define BUCK_CAP   3712      // mean 3200, sigma ~57 -> +9 sigma headroom
#define NBLK_STAGE 512       // blockIdx.x % 3 == 0 -> stage role (interleaved)
#define NBLK_GEMM1 1024
#define ELL_W      44        // Poisson(12.5) tail @44 ~ 3e-12/node
#define GNODES     64        // nodes per gather block (quarter bucket: grid 1564)
#define HPAD       80        // h row stride in LDS (elements); 160B, 16B-aligned

typedef unsigned int uint;
typedef __attribute__((ext_vector_type(8))) short bf16x8;
typedef __attribute__((ext_vector_type(4))) float f32x4;

static __device__ __forceinline__ uint pack_bf16x2(float a, float b) {
    unsigned short ua = __builtin_bit_cast(unsigned short, __float2bfloat16(a));
    unsigned short ub = __builtin_bit_cast(unsigned short, __float2bfloat16(b));
    return (uint)ua | ((uint)ub << 16);
}
static __device__ __forceinline__ short f2bf(float f) {
    return (short)__builtin_bit_cast(unsigned short, __float2bfloat16(f));
}

// 16-edge gather step, 64-wide rows (K2): DIRECT-index bpermute -> y1 row
// load -> unpack-accumulate.  2-deep chain, zero guards (pad lanes carry
// idx == N_NODES, the zeroed dummy row).
static __device__ __forceinline__ void gath16_64(
    const char* __restrict__ y1c, int e, int q4, uint pre, int idx,
    float& a0, float& a1, float& a2, float& a3)
{
    int s0 = __builtin_amdgcn_ds_bpermute(e * 4      + q4, idx);
    int s1 = __builtin_amdgcn_ds_bpermute(e * 4 + 16 + q4, idx);
    int s2 = __builtin_amdgcn_ds_bpermute(e * 4 + 32 + q4, idx);
    int s3 = __builtin_amdgcn_ds_bpermute(e * 4 + 48 + q4, idx);
    uint2 d0 = *(const uint2*)(y1c + ((size_t)(uint)s0 * 128u + pre));
    uint2 d1 = *(const uint2*)(y1c + ((size_t)(uint)s1 * 128u + pre));
    uint2 d2 = *(const uint2*)(y1c + ((size_t)(uint)s2 * 128u + pre));
    uint2 d3 = *(const uint2*)(y1c + ((size_t)(uint)s3 * 128u + pre));
    a0 += __uint_as_float(d0.x << 16) + __uint_as_float(d1.x << 16)
        + __uint_as_float(d2.x << 16) + __uint_as_float(d3.x << 16);
    a1 += __uint_as_float(d0.x & 0xffff0000u) + __uint_as_float(d1.x & 0xffff0000u)
        + __uint_as_float(d2.x & 0xffff0000u) + __uint_as_float(d3.x & 0xffff0000u);
    a2 += __uint_as_float(d0.y << 16) + __uint_as_float(d1.y << 16)
        + __uint_as_float(d2.y << 16) + __uint_as_float(d3.y << 16);
    a3 += __uint_as_float(d0.y & 0xffff0000u) + __uint_as_float(d1.y & 0xffff0000u)
        + __uint_as_float(d2.y & 0xffff0000u) + __uint_as_float(d3.y & 0xffff0000u);
}

// 16-edge gather step, 40-wide rows (K3): direct-idx bpermute -> y2 load.
static __device__ __forceinline__ void gath16_40(
    const char* __restrict__ y2c, int e, int p2, uint pre2, int idx,
    float& a0, float& a1)
{
    int s0 = __builtin_amdgcn_ds_bpermute(e * 4      + p2, idx);
    int s1 = __builtin_amdgcn_ds_bpermute(e * 4 +  8 + p2, idx);
    int s2 = __builtin_amdgcn_ds_bpermute(e * 4 + 16 + p2, idx);
    int s3 = __builtin_amdgcn_ds_bpermute(e * 4 + 24 + p2, idx);
    int s4 = __builtin_amdgcn_ds_bpermute(e * 4 + 32 + p2, idx);
    int s5 = __builtin_amdgcn_ds_bpermute(e * 4 + 40 + p2, idx);
    int s6 = __builtin_amdgcn_ds_bpermute(e * 4 + 48 + p2, idx);
    int s7 = __builtin_amdgcn_ds_bpermute(e * 4 + 56 + p2, idx);
    uint d0 = *(const uint*)(y2c + ((size_t)(uint)s0 * 80u + pre2));
    uint d1 = *(const uint*)(y2c + ((size_t)(uint)s1 * 80u + pre2));
    uint d2 = *(const uint*)(y2c + ((size_t)(uint)s2 * 80u + pre2));
    uint d3 = *(const uint*)(y2c + ((size_t)(uint)s3 * 80u + pre2));
    uint d4 = *(const uint*)(y2c + ((size_t)(uint)s4 * 80u + pre2));
    uint d5 = *(const uint*)(y2c + ((size_t)(uint)s5 * 80u + pre2));
    uint d6 = *(const uint*)(y2c + ((size_t)(uint)s6 * 80u + pre2));
    uint d7 = *(const uint*)(y2c + ((size_t)(uint)s7 * 80u + pre2));
    a0 += __uint_as_float(d0 << 16) + __uint_as_float(d1 << 16)
        + __uint_as_float(d2 << 16) + __uint_as_float(d3 << 16)
        + __uint_as_float(d4 << 16) + __uint_as_float(d5 << 16)
        + __uint_as_float(d6 << 16) + __uint_as_float(d7 << 16);
    a1 += __uint_as_float(d0 & 0xffff0000u) + __uint_as_float(d1 & 0xffff0000u)
        + __uint_as_float(d2 & 0xffff0000u) + __uint_as_float(d3 & 0xffff0000u)
        + __uint_as_float(d4 & 0xffff0000u) + __uint_as_float(d5 & 0xffff0000u)
        + __uint_as_float(d6 & 0xffff0000u) + __uint_as_float(d7 & 0xffff0000u);
}

// ---------------------------------------------------------------------------
// Fused K1: interleaved stage/gemm roles, static partition.
// launch_bounds(256, 3): the proven no-spill config (VGPR 72).  R8 showed
// (256,6) spills hard; R11 showed (256,4) trims VGPR to 64 with mild spill
// (+19% FETCH) and zero dur gain — K1 is chain-latency-bound, not
// wave-starved.  3 blocks/CU it is.
// ---------------------------------------------------------------------------
__global__ __launch_bounds__(256, 3) void stage_and_gemm1(
    const int* __restrict__ src, const int* __restrict__ dst,
    int* __restrict__ bucketCnt, uint* __restrict__ staged,
    const float* __restrict__ x,
    const float* __restrict__ W_l, const float* __restrict__ W_r,
    const float* __restrict__ b,
    __hip_bfloat16* __restrict__ y1, __hip_bfloat16* __restrict__ r1,
    __hip_bfloat16* __restrict__ y2, int ntiles)
{
    __shared__ int cntB[NBUCK], offB[NBUCK], gbase[NBUCK];

    if (blockIdx.x % 3 == 0) {
        const int sid = blockIdx.x / 3;
        const int per = (N_EDGES + NBLK_STAGE - 1) / NBLK_STAGE;   // 2442
        const int e0 = sid * per;
        const int e1 = (e0 + per < N_EDGES) ? e0 + per : N_EDGES;
        for (int i = threadIdx.x; i < NBUCK; i += 256) { cntB[i] = 0; offB[i] = 0; }
        __syncthreads();
        for (int e = e0 + threadIdx.x; e < e1; e += 256)
            atomicAdd(&cntB[dst[e] >> 8], 1);
        __syncthreads();
        for (int i = threadIdx.x; i < NBUCK; i += 256) {
            int c = cntB[i];
            gbase[i] = c ? atomicAdd(&bucketCnt[i], c) : 0;
        }
        __syncthreads();
        for (int e = e0 + threadIdx.x; e < e1; e += 256) {
            int d = dst[e];
            int s = src[e];
            int bk = d >> 8;
            int pos = gbase[bk] + atomicAdd(&offB[bk], 1);
            if (pos < BUCK_CAP)
                staged[(size_t)bk * BUCK_CAP + pos] =
                    (uint)s | ((uint)(d & 255) << 17);
        }
        return;
    }

    // ---- gemm1: gbid in [0, 1024) ----
    const int gbid = blockIdx.x - (blockIdx.x / 3 + 1);
    if (gbid == 0 && threadIdx.x < 64) {
        y1[(size_t)N_NODES * 64 + threadIdx.x] = __float2bfloat16(0.0f);
        if (threadIdx.x < N_CLS)
            y2[(size_t)N_NODES * N_CLS + threadIdx.x] = __float2bfloat16(0.0f);
    }

    const int lane = threadIdx.x & 63;
    const int m = lane & 15;
    const int q = lane >> 4;

    bf16x8 bfrag[8][2];
    float  biasv[4];
    #pragma unroll
    for (int t = 0; t < 8; ++t) {
        const float* Wsrc = (t < 4) ? W_l : W_r;
        const int c = t * 16 + m - ((t < 4) ? 0 : 64);
        #pragma unroll
        for (int ks = 0; ks < 2; ++ks) {
            bf16x8 f;
            #pragma unroll
            for (int j = 0; j < 8; ++j)
                f[j] = f2bf(Wsrc[(ks * 32 + q * 8 + j) * 64 + c]);
            bfrag[t][ks] = f;
        }
    }
    #pragma unroll
    for (int t = 0; t < 4; ++t) biasv[t] = b[t * 16 + m];

    int wid = gbid * 4 + (threadIdx.x >> 6);
    const int nw = NBLK_GEMM1 * 4;
    for (int tile = wid; tile < ntiles; tile += nw) {
        const int node0 = tile * 16;
        const float* xrow = x + (size_t)(node0 + m) * 64 + q * 8;
        bf16x8 afrag[2];
        #pragma unroll
        for (int ks = 0; ks < 2; ++ks) {
            float4 f0 = *(const float4*)(xrow + ks * 32);
            float4 f1 = *(const float4*)(xrow + ks * 32 + 4);
            bf16x8 a;
            a[0] = f2bf(f0.x); a[1] = f2bf(f0.y); a[2] = f2bf(f0.z); a[3] = f2bf(f0.w);
            a[4] = f2bf(f1.x); a[5] = f2bf(f1.y); a[6] = f2bf(f1.z); a[7] = f2bf(f1.w);
            afrag[ks] = a;
        }
        f32x4 acc[8];
        #pragma unroll
        for (int t = 0; t < 8; ++t) acc[t] = (f32x4){0.f, 0.f, 0.f, 0.f};
        #pragma unroll
        for (int ks = 0; ks < 2; ++ks) {
            #pragma unroll
            for (int t = 0; t < 8; ++t)
                acc[t] = __builtin_amdgcn_mfma_f32_16x16x32_bf16(
                    afrag[ks], bfrag[t][ks], acc[t], 0, 0, 0);
        }
        #pragma unroll
        for (int t = 0; t < 8; ++t) {
            #pragma unroll
            for (int r = 0; r < 4; ++r) {
                const size_t row = (size_t)(node0 + q * 4 + r);
                if (t < 4)
                    y1[row * 64 + t * 16 + m] = __float2bfloat16(acc[t][r]);
                else
                    r1[row * 64 + (t - 4) * 16 + m] =
                        __float2bfloat16(acc[t][r] + biasv[t - 4]);
            }
        }
    }
}

// ---------------------------------------------------------------------------
// K2: LDS-ELL build + pair-pipelined gather + relu + fused gemm2.
// GNODES=64 lets lslots hold FULL src ids as int (11.5 KB): the gather chain
// is 2-deep (bpermute -> row load), no staged re-deref, no inner guards.
// LDS ~22 KB -> 4 blocks/CU (32 waves, the cap); grid 1564 = ~6 blocks/CU
// of work with rotation rounds to smooth stragglers.
// ---------------------------------------------------------------------------
__global__ __launch_bounds__(512, 8) void gather1_gemm2(
    const __hip_bfloat16* __restrict__ y1,   // [N+1][64], row N zeroed
    const uint* __restrict__ staged, const int* __restrict__ bucketCnt,
    const __hip_bfloat16* __restrict__ r1,   // [N][64]
    const float* __restrict__ W_l, const float* __restrict__ W_r,
    const float* __restrict__ b,             // W2_l, W2_r, b2
    __hip_bfloat16* __restrict__ y2, __hip_bfloat16* __restrict__ r2)
{
    __shared__ int   lcnt[GNODES];
    __shared__ int   lslots[GNODES * ELL_W + 64];   // 11.5 KB (src ids)
    __shared__ short hls[GNODES * HPAD];            // 10.25 KB h tile

    const int pb = blockIdx.x >> 2;          // parent staging bucket
    const int qt = blockIdx.x & 3;           // which quarter we own
    const int node0 = pb * BUCK_NODES + qt * GNODES;

    for (int i = threadIdx.x; i < GNODES; i += 512) lcnt[i] = 0;
    __syncthreads();

    int total = bucketCnt[pb]; if (total > BUCK_CAP) total = BUCK_CAP;
    const uint* sp = staged + (size_t)pb * BUCK_CAP;
    const int rel0 = qt * GNODES;
    for (int i = threadIdx.x; i < total; i += 512) {
        uint v = sp[i];
        int rel = (int)(v >> 17) - rel0;
        if (0 <= rel && rel < GNODES) {
            int pos = atomicAdd(&lcnt[rel], 1);
            if (pos < ELL_W) lslots[rel * ELL_W + pos] = (int)(v & 0x1FFFFu);
        }
    }
    __syncthreads();

    const int lane = threadIdx.x & 63;
    const int wv   = threadIdx.x >> 6;       // 0..7
    const int q4   = (lane >> 4) * 4;
    const uint pre = (uint)(lane & 15) * 8u;
    const char* y1c = (const char*)y1;

    for (int n = wv; n < GNODES; n += 16) {
        const int nA = n, nB = n + 8;
        const int nodeA = node0 + nA, nodeB = node0 + nB;
        const bool vA = nodeA < N_NODES, vB = nodeB < N_NODES;
        const int degA = vA ? lcnt[nA] : 0;
        const int degB = vB ? lcnt[nB] : 0;
        const int dcA = degA < ELL_W ? degA : ELL_W;
        const int dcB = degB < ELL_W ? degB : ELL_W;
        const int idxA = (lane >= dcA) ? N_NODES : lslots[nA * ELL_W + lane];
        const int idxB = (lane >= dcB) ? N_NODES : lslots[nB * ELL_W + lane];

        uint2 rrA = *(const uint2*)((const char*)r1 +
                        ((size_t)(vA ? nodeA : 0) * 128u + pre));
        uint2 rrB = *(const uint2*)((const char*)r1 +
                        ((size_t)(vB ? nodeB : 0) * 128u + pre));

        float aA0 = 0.f, aA1 = 0.f, aA2 = 0.f, aA3 = 0.f;
        float aB0 = 0.f, aB1 = 0.f, aB2 = 0.f, aB3 = 0.f;

        gath16_64(y1c, 0, q4, pre, idxA, aA0, aA1, aA2, aA3);
        gath16_64(y1c, 0, q4, pre, idxB, aB0, aB1, aB2, aB3);
        for (int e = 16; e < ((dcA + 15) & ~15); e += 16)
            gath16_64(y1c, e, q4, pre, idxA, aA0, aA1, aA2, aA3);
        for (int e = 16; e < ((dcB + 15) & ~15); e += 16)
            gath16_64(y1c, e, q4, pre, idxB, aB0, aB1, aB2, aB3);

        aA0 += __shfl_xor(aA0, 16); aA0 += __shfl_xor(aA0, 32);
        aA1 += __shfl_xor(aA1, 16); aA1 += __shfl_xor(aA1, 32);
        aA2 += __shfl_xor(aA2, 16); aA2 += __shfl_xor(aA2, 32);
        aA3 += __shfl_xor(aA3, 16); aA3 += __shfl_xor(aA3, 32);
        aB0 += __shfl_xor(aB0, 16); aB0 += __shfl_xor(aB0, 32);
        aB1 += __shfl_xor(aB1, 16); aB1 += __shfl_xor(aB1, 32);
        aB2 += __shfl_xor(aB2, 16); aB2 += __shfl_xor(aB2, 32);
        aB3 += __shfl_xor(aB3, 16); aB3 += __shfl_xor(aB3, 32);

        const float invA = 1.0f / (float)(degA > 1 ? degA : 1);
        const float invB = 1.0f / (float)(degB > 1 ? degB : 1);

        float vA0 = aA0 * invA + __uint_as_float(rrA.x << 16);
        float vA1 = aA1 * invA + __uint_as_float(rrA.x & 0xffff0000u);
        float vA2 = aA2 * invA + __uint_as_float(rrA.y << 16);
        float vA3 = aA3 * invA + __uint_as_float(rrA.y & 0xffff0000u);
        vA0 = vA0 > 0.f ? vA0 : 0.f; vA1 = vA1 > 0.f ? vA1 : 0.f;
        vA2 = vA2 > 0.f ? vA2 : 0.f; vA3 = vA3 > 0.f ? vA3 : 0.f;
        float vB0 = aB0 * invB + __uint_as_float(rrB.x << 16);
        float vB1 = aB1 * invB + __uint_as_float(rrB.x & 0xffff0000u);
        float vB2 = aB2 * invB + __uint_as_float(rrB.y << 16);
        float vB3 = aB3 * invB + __uint_as_float(rrB.y & 0xffff0000u);
        vB0 = vB0 > 0.f ? vB0 : 0.f; vB1 = vB1 > 0.f ? vB1 : 0.f;
        vB2 = vB2 > 0.f ? vB2 : 0.f; vB3 = vB3 > 0.f ? vB3 : 0.f;

        if (lane < 16) {
            uint2 oA, oB;
            oA.x = pack_bf16x2(vA0, vA1); oA.y = pack_bf16x2(vA2, vA3);
            oB.x = pack_bf16x2(vB0, vB1); oB.y = pack_bf16x2(vB2, vB3);
            *(uint2*)(&hls[nA * HPAD + (lane & 15) * 4]) = oA;
            *(uint2*)(&hls[nB * HPAD + (lane & 15) * 4]) = oB;
        }
    }
    __syncthreads();

    // ---- fused gemm2: waves 0-3 each own one 16-row tile (64 rows) ----
    if (wv < 4) {
        const int m = lane & 15;
        const int q = lane >> 4;
        bf16x8 bfrag[5][2];
        float  biasv[5];
        #pragma unroll
        for (int t = 0; t < 5; ++t) {
            const int g = t * 16 + m;
            const float* Wsrc = (g < N_CLS) ? W_l : W_r;
            const int c = (g < N_CLS) ? g : g - N_CLS;
            #pragma unroll
            for (int ks = 0; ks < 2; ++ks) {
                bf16x8 f;
                #pragma unroll
                for (int j = 0; j < 8; ++j)
                    f[j] = f2bf(Wsrc[(ks * 32 + q * 8 + j) * N_CLS + c]);
                bfrag[t][ks] = f;
            }
            biasv[t] = (g >= N_CLS) ? b[g - N_CLS] : 0.0f;
        }

        const int trow0 = wv * 16;
        bf16x8 afrag[2];
        afrag[0] = *(const bf16x8*)(&hls[(trow0 + m) * HPAD + q * 8]);
        afrag[1] = *(const bf16x8*)(&hls[(trow0 + m) * HPAD + 32 + q * 8]);
        f32x4 acc[5];
        #pragma unroll
        for (int t = 0; t < 5; ++t) acc[t] = (f32x4){0.f, 0.f, 0.f, 0.f};
        #pragma unroll
        for (int ks = 0; ks < 2; ++ks) {
            #pragma unroll
            for (int t = 0; t < 5; ++t)
                acc[t] = __builtin_amdgcn_mfma_f32_16x16x32_bf16(
                    afrag[ks], bfrag[t][ks], acc[t], 0, 0, 0);
        }
        const int gnode0 = node0 + trow0;
        #pragma unroll
        for (int t = 0; t < 5; ++t) {
            const int g = t * 16 + m;
            #pragma unroll
            for (int r = 0; r < 4; ++r) {
                const int row = gnode0 + q * 4 + r;
                if (row < N_NODES) {
                    float v = acc[t][r] + biasv[t];
                    if (g < N_CLS) y2[(size_t)row * N_CLS + g] = __float2bfloat16(v);
                    else           r2[(size_t)row * N_CLS + (g - N_CLS)] = __float2bfloat16(v);
                }
            }
        }
    }
}

// ---------------------------------------------------------------------------
// K3: LDS-ELL build + pair-pipelined gather + log_softmax.  GNODES=64:
// grid 1564 -> 4 blocks/CU resident (32 waves).  LDS 11.6 KB.
// ---------------------------------------------------------------------------
__global__ __launch_bounds__(512, 8) void bucket_gather2(
    const __hip_bfloat16* __restrict__ y2,   // [N+1][40], row N zeroed
    const __hip_bfloat16* __restrict__ r2,   // [N][40]
    const uint* __restrict__ staged, const int* __restrict__ bucketCnt,
    float* __restrict__ out)
{
    __shared__ int lcnt[GNODES];
    __shared__ int lslots[GNODES * ELL_W + 64];
    const int pb = blockIdx.x >> 2;
    const int qt = blockIdx.x & 3;
    const int node0 = pb * BUCK_NODES + qt * GNODES;

    for (int i = threadIdx.x; i < GNODES; i += 512) lcnt[i] = 0;
    __syncthreads();

    int total = bucketCnt[pb]; if (total > BUCK_CAP) total = BUCK_CAP;
    const uint* sp = staged + (size_t)pb * BUCK_CAP;
    const int rel0 = qt * GNODES;
    for (int i = threadIdx.x; i < total; i += 512) {
        uint v = sp[i];
        int rel = (int)(v >> 17) - rel0;
        if (0 <= rel && rel < GNODES) {
            int pos = atomicAdd(&lcnt[rel], 1);
            if (pos < ELL_W) lslots[rel * ELL_W + pos] = (int)(v & 0x1FFFFu);
        }
    }
    __syncthreads();

    const int lane  = threadIdx.x & 63;
    const int wv    = threadIdx.x >> 6;
    const int lpair = lane & 31;
    const int p2    = (lane >> 5) * 4;
    const uint pre2 = (uint)(lpair < 20 ? lpair : 19) * 4u;
    const char* y2c = (const char*)y2;

    for (int n = wv; n < GNODES; n += 16) {
        const int nA = n, nB = n + 8;
        const int nodeA = node0 + nA, nodeB = node0 + nB;
        const bool vA = nodeA < N_NODES, vB = nodeB < N_NODES;
        const int degA = vA ? lcnt[nA] : 0;
        const int degB = vB ? lcnt[nB] : 0;
        const int dcA = degA < ELL_W ? degA : ELL_W;
        const int dcB = degB < ELL_W ? degB : ELL_W;
        const int idxA = (lane >= dcA) ? N_NODES : lslots[nA * ELL_W + lane];
        const int idxB = (lane >= dcB) ? N_NODES : lslots[nB * ELL_W + lane];

        uint rrA = *(const uint*)((const char*)r2 +
                       ((size_t)(vA ? nodeA : 0) * 80u + pre2));
        uint rrB = *(const uint*)((const char*)r2 +
                       ((size_t)(vB ? nodeB : 0) * 80u + pre2));

        float aA0 = 0.f, aA1 = 0.f, aB0 = 0.f, aB1 = 0.f;
        gath16_40(y2c, 0, p2, pre2, idxA, aA0, aA1);
        gath16_40(y2c, 0, p2, pre2, idxB, aB0, aB1);
        for (int e = 16; e < ((dcA + 15) & ~15); e += 16)
            gath16_40(y2c, e, p2, pre2, idxA, aA0, aA1);
        for (int e = 16; e < ((dcB + 15) & ~15); e += 16)
            gath16_40(y2c, e, p2, pre2, idxB, aB0, aB1);

        aA0 += __shfl_xor(aA0, 32);
        aA1 += __shfl_xor(aA1, 32);
        aB0 += __shfl_xor(aB0, 32);
        aB1 += __shfl_xor(aB1, 32);

        const float invA = 1.0f / (float)(degA > 1 ? degA : 1);
        const float invB = 1.0f / (float)(degB > 1 ? degB : 1);
        float lA0 = aA0 * invA + __uint_as_float(rrA << 16);
        float lA1 = aA1 * invA + __uint_as_float(rrA & 0xffff0000u);
        float lB0 = aB0 * invB + __uint_as_float(rrB << 16);
        float lB1 = aB1 * invB + __uint_as_float(rrB & 0xffff0000u);
        if (lpair >= 20) { lA0 = -INFINITY; lA1 = -INFINITY;
                           lB0 = -INFINITY; lB1 = -INFINITY; }

        float mA = fmaxf(lA0, lA1);
        float mB = fmaxf(lB0, lB1);
        #pragma unroll
        for (int off = 16; off > 0; off >>= 1) {
            mA = fmaxf(mA, __shfl_xor(mA, off));
            mB = fmaxf(mB, __shfl_xor(mB, off));
        }
        float exA = (lpair < 20) ? (expf(lA0 - mA) + expf(lA1 - mA)) : 0.0f;
        float exB = (lpair < 20) ? (expf(lB0 - mB) + expf(lB1 - mB)) : 0.0f;
        #pragma unroll
        for (int off = 16; off > 0; off >>= 1) {
            exA += __shfl_xor(exA, off);
            exB += __shfl_xor(exB, off);
        }
        float lgA = mA + logf(exA);
        float lgB = mB + logf(exB);
        if (vA && lane < 20) {
            float2 o = make_float2(lA0 - lgA, lA1 - lgA);
            *(float2*)(out + (size_t)nodeA * N_CLS + lpair * 2) = o;
        }
        if (vB && lane < 20) {
            float2 o = make_float2(lB0 - lgB, lB1 - lgB);
            *(float2*)(out + (size_t)nodeB * N_CLS + lpair * 2) = o;
        }
    }
}

extern "C" void kernel_launch(void* const* d_in, const int* in_sizes, int n_in,
                              void* d_out, int out_size, void* d_ws, size_t ws_size,
                              hipStream_t stream)
{
    (void)in_sizes; (void)n_in; (void)out_size; (void)ws_size;

    const float* x    = (const float*)d_in[0];
    const int*   ei   = (const int*)d_in[1];      // [2, E]: src row, then dst row
    const float* W1_l = (const float*)d_in[2];
    const float* b1   = (const float*)d_in[3];
    const float* W1_r = (const float*)d_in[4];
    const float* W2_l = (const float*)d_in[5];
    const float* b2   = (const float*)d_in[6];
    const float* W2_r = (const float*)d_in[7];
    float* out = (float*)d_out;

    const int* src = ei;
    const int* dst = ei + N_EDGES;

    // workspace layout (bytes, ~51 MiB):
    //   bucketCnt : [0, 1564)                int[NBUCK]
    //   staged    : [1M, +5.81MB)            u32[NBUCK*BUCK_CAP]
    //   y1        : [8M, +12.81MB)           bf16[(N+1)*64]
    //   r1        : [21M, +12.8MB)           bf16[N*64]
    //   y2        : [34M, +8.01MB)           bf16[(N+1)*40]
    //   r2        : [43M, +8MB)              bf16[N*40]
    char* ws = (char*)d_ws;
    int*            bucketCnt = (int*)(ws);
    uint*           staged    = (uint*)(ws + 1048576u);
    __hip_bfloat16* y1        = (__hip_bfloat16*)(ws + 8388608u);
    __hip_bfloat16* r1        = (__hip_bfloat16*)(ws + 22020096u);
    __hip_bfloat16* y2        = (__hip_bfloat16*)(ws + 35651584u);
    __hip_bfloat16* r2        = (__hip_bfloat16*)(ws + 45088768u);

    const int ntiles = N_NODES / 16;   // 6250, exact

    // K0: zero bucket counters
    hipMemsetAsync(ws, 0, 4096, stream);

    // K1: edge bucketing || gemm1 (static partition, interleaved roles)
    stage_and_gemm1<<<NBLK_STAGE + NBLK_GEMM1, 256, 0, stream>>>(
        src, dst, bucketCnt, staged, x, W1_l, W1_r, b1, y1, r1, y2, ntiles);

    // K2: LDS-ELL build + pair-pipelined gather (2-deep) + relu + fused gemm2
    gather1_gemm2<<<NBUCK * 4, 512, 0, stream>>>(
        y1, staged, bucketCnt, r1, W2_l, W2_r, b2, y2, r2);

    // K3: LDS-ELL build + pair-pipelined gather + log_softmax
    bucket_gather2<<<NBUCK * 4, 512, 0, stream>>>(y2, r2, staged, bucketCnt, out);
}